// Round 14
// baseline (361.200 us; speedup 1.0000x reference)
//
#include <hip/hip_runtime.h>
#include <math.h>

// SoftclDiceLoss on (B,C,D,H,W) = (2,1,64,256,256) float32.
// R14 = R10 byte-for-byte (proven best: CD=16, grid 512, x ring-4, srm ring-2,
// ONE barrier per segment, merged chains, LDS reads for xm/xc) + prep folded
// into staging via wave-uniform mode functor:
//   mode 0: x = A[i] ; mode 1: x = A[i]*B[i] ; mode 2: x = sigmoid(A[i])*B[i]
// -> no prep kernel, no pred/tgt buffers (saves 1 dispatch + 167 MB traffic).
// R13's register carries are REVERTED (A/B showed +13 us/dispatch VALU cost).

constexpr int Bn = 2;
constexpr int D  = 64;
constexpr int H  = 256;
constexpr int W  = 256;
constexpr int HW = H * W;           // 65536
constexpr int NV = Bn * D * H * W;  // 8388608

constexpr int CD  = 16;             // D-chunk per block
constexpr int XSF = 76;             // x LDS row stride (19 quads, odd)
constexpr int RSF = 68;             // rowmax LDS row stride (17 quads, odd)
// x plane: 36 rows (gh = h0-2+row), 18 quads (gw = w0-4+4q)
// rowmax:  34 rows (mp row mr, gh = h0-1+mr), cols = output cols w0..w0+63

__device__ __forceinline__ float4 vmin4(float4 a, float4 b) {
    return make_float4(fminf(a.x,b.x), fminf(a.y,b.y), fminf(a.z,b.z), fminf(a.w,b.w));
}
__device__ __forceinline__ float4 vmax4(float4 a, float4 b) {
    return make_float4(fmaxf(a.x,b.x), fmaxf(a.y,b.y), fmaxf(a.z,b.z), fmaxf(a.w,b.w));
}
__device__ __forceinline__ float4 sh1(float4 a, float4 b) { return make_float4(a.y,a.z,a.w,b.x); }
__device__ __forceinline__ float4 sh3(float4 a, float4 b) { return make_float4(a.w,b.x,b.y,b.z); }

// mode 0: a ; mode 1: a*b ; mode 2: sigmoid(a)*b   (mode is wave-uniform)
__device__ __forceinline__ float4 apply_mode(float4 a, const float* __restrict__ pb,
                                             long ix, int mode) {
    if (mode != 0) {
        if (mode == 2) {
            a.x = 1.0f / (1.0f + expf(-a.x));
            a.y = 1.0f / (1.0f + expf(-a.y));
            a.z = 1.0f / (1.0f + expf(-a.z));
            a.w = 1.0f / (1.0f + expf(-a.w));
        }
        float4 m = *(const float4*)(pb + ix);
        a.x *= m.x; a.y *= m.y; a.z *= m.z; a.w *= m.w;
    }
    return a;
}

template <bool FINAL>
__global__ __launch_bounds__(256) void skel_iter_kernel(
        const float* __restrict__ iA0, const float* __restrict__ iB0, int im0,
        float* __restrict__ out0,
        const float* __restrict__ oA0, const float* __restrict__ oB0, int om0,
        double* __restrict__ acc0,
        const float* __restrict__ iA1, const float* __restrict__ iB1, int im1,
        float* __restrict__ out1,
        const float* __restrict__ oA1, const float* __restrict__ oB1, int om1,
        double* __restrict__ acc1) {
    __shared__ float sx[4][36 * XSF];   // x ring of 4 (43.8 KB)
    __shared__ float srm[2][34 * RSF];  // rowmax ring of 2 (18.5 KB)

    // XCD-chunked swizzle
    int cpx = gridDim.x >> 3;
    int hwb = blockIdx.x;
    int bx  = (hwb & 7) * cpx + (hwb >> 3);

    int t   = bx >> 8;                 // tensor select (0 when grid=256)
    int bt  = bx & 255;
    int w0  = (bt & 3) * 64;
    int h0  = ((bt >> 2) & 7) * 32;
    int gd0 = ((bt >> 5) & 3) * CD;
    int b   = (bt >> 7) & 1;

    const float* iA = t ? iA1 : iA0;
    const float* iB = t ? iB1 : iB0;
    int          im = t ? im1 : im0;
    float*     xout = t ? out1 : out0;
    const float* oA = t ? oA1 : oA0;
    const float* oB = t ? oB1 : oB0;
    int          om = t ? om1 : om0;
    double*    accp = t ? acc1 : acc0;

    long base = (long)b * (D * HW);
    const float* xbA = iA + base;
    const float* xbB = iB ? iB + base : nullptr;
    float*       ob  = xout ? xout + base : nullptr;
    const float* obA = oA ? oA + base : nullptr;
    const float* obB = oB ? oB + base : nullptr;

    int tid = threadIdx.x;
    int r   = tid >> 3;   // 0..31 output row
    int k   = tid & 7;    // 0..7  8-col job

    const float4 INF4  = make_float4( INFINITY,  INFINITY,  INFINITY,  INFINITY);
    const float4 NINF4 = make_float4(-INFINITY, -INFINITY, -INFINITY, -INFINITY);

    // staging map: 648 quads (36 rows x 18), 3 rounds of 256
    int j1 = tid + 256, j2 = tid + 512;
    int sr0 = tid / 18, sq0 = tid - sr0 * 18;
    int sr1 = j1 / 18,  sq1 = j1 - sr1 * 18;
    int sr2 = j2 / 18,  sq2 = j2 - sr2 * 18;
    bool has2 = (j2 < 648);

    float4 Pa, Pb, Pc;   // pending plane
    auto issue = [&](int p) {
        if (p < 0 || p >= D) { Pa = Pb = Pc = INF4; return; }
        long pbase = (long)p * HW;
        auto f = [&](int row, int qd) -> float4 {
            int gh = h0 - 2 + row;
            int gw = w0 - 4 + 4 * qd;
            if ((unsigned)gh < (unsigned)H && (unsigned)gw < (unsigned)W) {
                long ix = pbase + gh * W + gw;
                float4 a = *(const float4*)(xbA + ix);
                return apply_mode(a, xbB, ix, im);
            }
            return INF4;
        };
        Pa = f(sr0, sq0);
        Pb = f(sr1, sq1);
        Pc = has2 ? f(sr2, sq2) : INF4;
    };
    auto commitv = [&](int p, float4 va, float4 vb, float4 vc) {
        float* dst = sx[(p + 4) & 3];
        *(float4*)&dst[sr0 * XSF + 4 * sq0] = va;
        *(float4*)&dst[sr1 * XSF + 4 * sq1] = vb;
        if (has2) *(float4*)&dst[sr2 * XSF + 4 * sq2] = vc;
    };

    // Prologue: planes gd0-2..gd0 resident; x[gd0+1] pending.
    issue(gd0 - 2); commitv(gd0 - 2, Pa, Pb, Pc);
    issue(gd0 - 1); commitv(gd0 - 1, Pa, Pb, Pc);
    issue(gd0);     commitv(gd0,     Pa, Pb, Pc);
    issue(gd0 + 1);
    __syncthreads();

    float4 h1lo=NINF4, h1hi=NINF4, h2lo=NINF4, h2hi=NINF4;  // hw9 ring
    float4 p1lo=NINF4, p1hi=NINF4, p2lo=NINF4, p2hi=NINF4;  // mp centers
    float4 rmplo=NINF4, rmphi=NINF4;                        // reg rowmax of s-1
    float4 xplo=INF4, xphi=INF4;                            // x center of s-2
    double s0 = 0.0, s1 = 0.0;

    for (int s = gd0 - 1; s <= gd0 + CD + 1; ++s) {
        // ---- staging: commit x[s+2] (captured), issue x[s+3] ----
        float4 Ta = Pa, Tb = Pb, Tc = Pc;
        if (s + 3 <= gd0 + CD + 1) issue(s + 3);
        if (s + 2 <= gd0 + CD + 1) commitv(s + 2, Ta, Tb, Tc);

        // ---- B(s): mp row r+1 in regs, rowmax -> srm[s&1] ----
        bool sv = (s >= 0 && s < D && s <= gd0 + CD);
        float4 lo = NINF4, hi = NINF4, rmlo = NINF4, rmhi = NINF4;
        if (sv) {
            const float* xq = sx[(s + 4) & 3];
            const float* xm = sx[(s + 3) & 3];
            const float* xp = sx[(s + 5) & 3];
            {
                const float* rc  = &xq[(r + 2) * XSF + 8 * k];
                const float* ru  = &xq[(r + 1) * XSF + 8 * k];
                const float* rd  = &xq[(r + 3) * XSF + 8 * k];
                const float* rm_ = &xm[(r + 2) * XSF + 8 * k];
                const float* rp_ = &xp[(r + 2) * XSF + 8 * k];
                float4 X0 = *(const float4*)rc,        X1 = *(const float4*)(rc + 4),
                       X2 = *(const float4*)(rc + 8),  X3 = *(const float4*)(rc + 12);
                float4 U1 = *(const float4*)(ru + 4),  U2 = *(const float4*)(ru + 8);
                float4 Dn1= *(const float4*)(rd + 4),  Dn2= *(const float4*)(rd + 8);
                float4 M1 = *(const float4*)(rm_ + 4), M2 = *(const float4*)(rm_ + 8);
                float4 P1 = *(const float4*)(rp_ + 4), P2 = *(const float4*)(rp_ + 8);
                lo = vmin4(vmin4(sh3(X0, X1), X1), sh1(X1, X2));
                lo = vmin4(lo, vmin4(vmin4(U1, Dn1), vmin4(M1, P1)));
                hi = vmin4(vmin4(sh3(X1, X2), X2), sh1(X2, X3));
                hi = vmin4(hi, vmin4(vmin4(U2, Dn2), vmin4(M2, P2)));
                float eL = __shfl_up(hi.w, 1);
                float eR = __shfl_down(lo.x, 1);
                if (k == 0) {
                    eL = -INFINITY;
                    if (w0 > 0) {
                        float w3 = fminf(fminf(X0.z, X0.w), X1.x);
                        eL = fminf(fminf(w3, fminf(ru[3], rd[3])),
                                   fminf(rm_[3], rp_[3]));
                    }
                }
                if (k == 7) {
                    eR = -INFINITY;
                    if (w0 + 64 < W) {
                        float w3 = fminf(fminf(X2.w, X3.x), X3.y);
                        eR = fminf(fminf(w3, fminf(ru[12], rd[12])),
                                   fminf(rm_[12], rp_[12]));
                    }
                }
                rmlo = vmax4(vmax4(make_float4(eL, lo.x, lo.y, lo.z), lo),
                             make_float4(lo.y, lo.z, lo.w, hi.x));
                rmhi = vmax4(vmax4(make_float4(lo.w, hi.x, hi.y, hi.z), hi),
                             make_float4(hi.y, hi.z, hi.w, eR));
                float* rw = &srm[s & 1][(r + 1) * RSF + 8 * k];
                *(float4*)rw       = rmlo;
                *(float4*)(rw + 4) = rmhi;
            }
            if (tid < 16) {    // halo rows 0 and 33, fully in-thread
                int mr2 = (tid >> 3) ? 33 : 0;
                int k2  = tid & 7;
                int gh2 = h0 - 1 + mr2;
                float4 hlo = NINF4, hhi = NINF4;
                if ((unsigned)gh2 < (unsigned)H) {
                    int xr2 = mr2 + 1;
                    const float* rc  = &xq[xr2 * XSF + 8 * k2];
                    const float* ru  = &xq[(xr2 - 1) * XSF + 8 * k2];
                    const float* rd  = &xq[(xr2 + 1) * XSF + 8 * k2];
                    const float* rm_ = &xm[xr2 * XSF + 8 * k2];
                    const float* rp_ = &xp[xr2 * XSF + 8 * k2];
                    float4 X0 = *(const float4*)rc,        X1 = *(const float4*)(rc + 4),
                           X2 = *(const float4*)(rc + 8),  X3 = *(const float4*)(rc + 12);
                    float4 U1 = *(const float4*)(ru + 4),  U2 = *(const float4*)(ru + 8);
                    float4 Dn1= *(const float4*)(rd + 4),  Dn2= *(const float4*)(rd + 8);
                    float4 M1 = *(const float4*)(rm_ + 4), M2 = *(const float4*)(rm_ + 8);
                    float4 P1 = *(const float4*)(rp_ + 4), P2 = *(const float4*)(rp_ + 8);
                    float4 l2 = vmin4(vmin4(sh3(X0, X1), X1), sh1(X1, X2));
                    l2 = vmin4(l2, vmin4(vmin4(U1, Dn1), vmin4(M1, P1)));
                    float4 g2 = vmin4(vmin4(sh3(X1, X2), X2), sh1(X2, X3));
                    g2 = vmin4(g2, vmin4(vmin4(U2, Dn2), vmin4(M2, P2)));
                    float eL2 = -INFINITY, eR2 = -INFINITY;
                    if (w0 + 8 * k2 - 1 >= 0) {
                        float w3 = fminf(fminf(X0.z, X0.w), X1.x);
                        eL2 = fminf(fminf(w3, fminf(ru[3], rd[3])),
                                    fminf(rm_[3], rp_[3]));
                    }
                    if (w0 + 8 * k2 + 8 < W) {
                        float w3 = fminf(fminf(X2.w, X3.x), X3.y);
                        eR2 = fminf(fminf(w3, fminf(ru[12], rd[12])),
                                    fminf(rm_[12], rp_[12]));
                    }
                    hlo = vmax4(vmax4(make_float4(eL2, l2.x, l2.y, l2.z), l2),
                                make_float4(l2.y, l2.z, l2.w, g2.x));
                    hhi = vmax4(vmax4(make_float4(l2.w, g2.x, g2.y, g2.z), g2),
                                make_float4(g2.y, g2.z, g2.w, eR2));
                }
                float* hw = &srm[s & 1][mr2 * RSF + 8 * k2];
                *(float4*)hw       = hlo;
                *(float4*)(hw + 4) = hhi;
            }
        }

        // ---- xc: x center of plane s-1 (slot (s+3)&3; commit wrote (s+2)&3) ----
        int dm = s - 1;
        float4 xclo = INF4, xchi = INF4;
        if (dm >= gd0 && dm <= gd0 + CD - 1) {
            const float* xd = sx[(dm + 4) & 3];
            xclo = *(const float4*)&xd[(r + 2) * XSF + 8 * k + 4];
            xchi = *(const float4*)&xd[(r + 2) * XSF + 8 * k + 8];
        }

        // ---- H(s-1): hw9 of plane s-1 (rm written last segment + reg row) ----
        float4 hclo = NINF4, hchi = NINF4;
        if (s >= gd0 && dm >= 0 && dm < D) {
            const float* m = srm[dm & 1];
            float4 a0 = *(const float4*)&m[r * RSF + 8 * k];
            float4 a1 = *(const float4*)&m[r * RSF + 8 * k + 4];
            float4 b0 = *(const float4*)&m[(r + 2) * RSF + 8 * k];
            float4 b1 = *(const float4*)&m[(r + 2) * RSF + 8 * k + 4];
            hclo = vmax4(vmax4(a0, rmplo), b0);
            hchi = vmax4(vmax4(a1, rmphi), b1);
        }

        // ---- C(s-2): output d = s-2 (registers only + global) ----
        int d = s - 2;
        if (d >= gd0 && d <= gd0 + CD - 1) {
            float4 mxlo = vmax4(h2lo, vmax4(h1lo, hclo));
            float4 mxhi = vmax4(h2hi, vmax4(h1hi, hchi));
            float4 rlo, rhi;
            rlo.x = fmaxf(xplo.x - (mxlo.x - p2lo.x), 0.0f);
            rlo.y = fmaxf(xplo.y - (mxlo.y - p2lo.y), 0.0f);
            rlo.z = fmaxf(xplo.z - (mxlo.z - p2lo.z), 0.0f);
            rlo.w = fmaxf(xplo.w - (mxlo.w - p2lo.w), 0.0f);
            rhi.x = fmaxf(xphi.x - (mxhi.x - p2hi.x), 0.0f);
            rhi.y = fmaxf(xphi.y - (mxhi.y - p2hi.y), 0.0f);
            rhi.z = fmaxf(xphi.z - (mxhi.z - p2hi.z), 0.0f);
            rhi.w = fmaxf(xphi.w - (mxhi.w - p2hi.w), 0.0f);
            long off = (long)d * HW + (h0 + r) * W + (w0 + 8 * k);
            if constexpr (FINAL) {
                float4 o1 = *(const float4*)(obA + off);
                o1 = apply_mode(o1, obB, off, om);
                float4 o2 = *(const float4*)(obA + off + 4);
                o2 = apply_mode(o2, obB, off + 4, om);
                s0 += (double)(rlo.x * o1.x) + (double)(rlo.y * o1.y)
                    + (double)(rlo.z * o1.z) + (double)(rlo.w * o1.w)
                    + (double)(rhi.x * o2.x) + (double)(rhi.y * o2.y)
                    + (double)(rhi.z * o2.z) + (double)(rhi.w * o2.w);
                s1 += (double)rlo.x + (double)rlo.y + (double)rlo.z + (double)rlo.w
                    + (double)rhi.x + (double)rhi.y + (double)rhi.z + (double)rhi.w;
            } else {
                *(float4*)(ob + off)     = rlo;
                *(float4*)(ob + off + 4) = rhi;
            }
        }

        // ---- shifts ----
        h2lo = h1lo; h2hi = h1hi; h1lo = hclo; h1hi = hchi;
        p2lo = p1lo; p2hi = p1hi; p1lo = lo;   p1hi = hi;
        rmplo = rmlo; rmphi = rmhi;
        xplo = xclo;  xphi = xchi;

        __syncthreads();   // the ONLY barrier per segment
    }

    if constexpr (FINAL) {
        for (int off = 32; off > 0; off >>= 1) {
            s0 += __shfl_down(s0, off, 64);
            s1 += __shfl_down(s1, off, 64);
        }
        if ((tid & 63) == 0) {
            atomicAdd(&accp[0], s0);
            atomicAdd(&accp[1], s1);
        }
    }
}

__global__ void final_kernel(const double* __restrict__ acc, float* __restrict__ out) {
    double clrecall = (acc[0] + 1e-12) / (acc[1] + 1e-12);
    double clacc    = (acc[2] + 1e-12) / (acc[3] + 1e-12);
    double cldice   = 2.0 * clrecall * clacc / (clrecall + clacc + 1e-12);
    out[0] = (float)(1.0 - cldice);
}

extern "C" void kernel_launch(void* const* d_in, const int* in_sizes, int n_in,
                              void* d_out, int out_size, void* d_ws, size_t ws_size,
                              hipStream_t stream) {
    const float* logits = (const float*)d_in[0];
    const float* target = (const float*)d_in[1];
    const float* mask   = (const float*)d_in[2];
    float* out = (float*)d_out;

    // Workspace (floats): A0 | B0 | A1 | B1 | acc(4 doubles)
    float* A0 = (float*)d_ws;
    float* B0 = A0 + NV;

    bool big = ws_size >= (size_t)4 * NV * 4 + 64;
    float* A1   = big ? (B0 + NV) : A0;
    float* B1   = big ? (A1 + NV) : B0;
    double* acc = big ? (double*)(B1 + NV) : (double*)(B0 + NV);

    hipMemsetAsync(acc, 0, 4 * sizeof(double), stream);

    dim3 blk(256);
    const float* Z = nullptr;

    if (big) {
        dim3 g(512);   // 2 tensors x 256 blocks; 2 blocks/CU, all resident
        // chain0: skel(target*mask); chain1: skel(sigmoid(logits)*mask)
        skel_iter_kernel<false><<<g, blk, 0, stream>>>(
            target, mask, 1, A0, Z, Z, 0, acc,
            logits, mask, 2, A1, Z, Z, 0, acc + 2);
        skel_iter_kernel<false><<<g, blk, 0, stream>>>(
            A0, Z, 0, B0, Z, Z, 0, acc,
            A1, Z, 0, B1, Z, Z, 0, acc + 2);
        skel_iter_kernel<false><<<g, blk, 0, stream>>>(
            B0, Z, 0, A0, Z, Z, 0, acc,
            B1, Z, 0, A1, Z, Z, 0, acc + 2);
        skel_iter_kernel<false><<<g, blk, 0, stream>>>(
            A0, Z, 0, B0, Z, Z, 0, acc,
            A1, Z, 0, B1, Z, Z, 0, acc + 2);
        // FINAL: chain0 vs pred (mode 2), chain1 vs tgt (mode 1)
        skel_iter_kernel<true><<<g, blk, 0, stream>>>(
            B0, Z, 0, nullptr, logits, mask, 2, acc,
            B1, Z, 0, nullptr, target, mask, 1, acc + 2);
    } else {
        dim3 g(256);   // sequential fallback (t = 0 always)
        skel_iter_kernel<false><<<g, blk, 0, stream>>>(
            target, mask, 1, A0, Z, Z, 0, acc,
            target, mask, 1, A0, Z, Z, 0, acc);
        skel_iter_kernel<false><<<g, blk, 0, stream>>>(
            A0, Z, 0, B0, Z, Z, 0, acc, A0, Z, 0, B0, Z, Z, 0, acc);
        skel_iter_kernel<false><<<g, blk, 0, stream>>>(
            B0, Z, 0, A0, Z, Z, 0, acc, B0, Z, 0, A0, Z, Z, 0, acc);
        skel_iter_kernel<false><<<g, blk, 0, stream>>>(
            A0, Z, 0, B0, Z, Z, 0, acc, A0, Z, 0, B0, Z, Z, 0, acc);
        skel_iter_kernel<true><<<g, blk, 0, stream>>>(
            B0, Z, 0, nullptr, logits, mask, 2, acc,
            B0, Z, 0, nullptr, logits, mask, 2, acc);
        skel_iter_kernel<false><<<g, blk, 0, stream>>>(
            logits, mask, 2, A0, Z, Z, 0, acc + 2,
            logits, mask, 2, A0, Z, Z, 0, acc + 2);
        skel_iter_kernel<false><<<g, blk, 0, stream>>>(
            A0, Z, 0, B0, Z, Z, 0, acc + 2, A0, Z, 0, B0, Z, Z, 0, acc + 2);
        skel_iter_kernel<false><<<g, blk, 0, stream>>>(
            B0, Z, 0, A0, Z, Z, 0, acc + 2, B0, Z, 0, A0, Z, Z, 0, acc + 2);
        skel_iter_kernel<false><<<g, blk, 0, stream>>>(
            A0, Z, 0, B0, Z, Z, 0, acc + 2, A0, Z, 0, B0, Z, Z, 0, acc + 2);
        skel_iter_kernel<true><<<g, blk, 0, stream>>>(
            B0, Z, 0, nullptr, target, mask, 1, acc + 2,
            B0, Z, 0, nullptr, target, mask, 1, acc + 2);
    }

    final_kernel<<<1, 1, 0, stream>>>(acc, out);
}

// Round 15
// 314.035 us; speedup vs baseline: 1.1502x; 1.1502x over previous
//
#include <hip/hip_runtime.h>
#include <math.h>

// SoftclDiceLoss on (B,C,D,H,W) = (2,1,64,256,256) float32.
// R15 = R10 byte-for-byte (proven 331us: CD=16, grid 512, x ring-4, srm
// ring-2, ONE barrier/segment, merged chains, prep kernel, 4-buffer ws)
// + ONE change: the segment barrier is a raw s_barrier preceded by
// s_waitcnt lgkmcnt(0) ONLY (no vmcnt drain). __syncthreads() forces
// vmcnt(0) before s_barrier [HIP-compiler], which drains the plane-(s+3)
// prefetch issued this segment and exposes full L2/L3 latency every
// segment. LDS visibility needs only lgkmcnt(0); the in-flight global
// loads target private registers (compiler inserts counted vmcnt before
// their first use next segment).

constexpr int Bn = 2;
constexpr int D  = 64;
constexpr int H  = 256;
constexpr int W  = 256;
constexpr int HW = H * W;           // 65536
constexpr int NV = Bn * D * H * W;  // 8388608

constexpr int CD  = 16;             // D-chunk per block
constexpr int XSF = 76;             // x LDS row stride (19 quads, odd)
constexpr int RSF = 68;             // rowmax LDS row stride (17 quads, odd)

__device__ __forceinline__ void lds_barrier() {
    // LDS-only drain + raw barrier: leaves global loads in flight across
    // the barrier (T4 pattern). Memory clobbers fence LDS access motion.
    asm volatile("s_waitcnt lgkmcnt(0)" ::: "memory");
    __builtin_amdgcn_s_barrier();
    asm volatile("" ::: "memory");
}

__device__ __forceinline__ float4 vmin4(float4 a, float4 b) {
    return make_float4(fminf(a.x,b.x), fminf(a.y,b.y), fminf(a.z,b.z), fminf(a.w,b.w));
}
__device__ __forceinline__ float4 vmax4(float4 a, float4 b) {
    return make_float4(fmaxf(a.x,b.x), fmaxf(a.y,b.y), fmaxf(a.z,b.z), fmaxf(a.w,b.w));
}
__device__ __forceinline__ float4 sh1(float4 a, float4 b) { return make_float4(a.y,a.z,a.w,b.x); }
__device__ __forceinline__ float4 sh3(float4 a, float4 b) { return make_float4(a.w,b.x,b.y,b.z); }

__global__ __launch_bounds__(256) void prep_kernel(const float* __restrict__ logits,
                                                   const float* __restrict__ target,
                                                   const float* __restrict__ mask,
                                                   float* __restrict__ pred,
                                                   float* __restrict__ tgt) {
    int i = (blockIdx.x * 256 + threadIdx.x) * 4;
    float4 lg = *(const float4*)(logits + i);
    float4 tg = *(const float4*)(target + i);
    float4 mk = *(const float4*)(mask + i);
    float4 p, t;
    p.x = (1.0f/(1.0f+expf(-lg.x)))*mk.x;  t.x = tg.x*mk.x;
    p.y = (1.0f/(1.0f+expf(-lg.y)))*mk.y;  t.y = tg.y*mk.y;
    p.z = (1.0f/(1.0f+expf(-lg.z)))*mk.z;  t.z = tg.z*mk.z;
    p.w = (1.0f/(1.0f+expf(-lg.w)))*mk.w;  t.w = tg.w*mk.w;
    *(float4*)(pred + i) = p;
    *(float4*)(tgt + i)  = t;
}

template <bool FINAL>
__global__ __launch_bounds__(256) void skel_iter_kernel(
        const float* __restrict__ in0, float* __restrict__ out0,
        const float* __restrict__ oth0, double* __restrict__ acc0,
        const float* __restrict__ in1, float* __restrict__ out1,
        const float* __restrict__ oth1, double* __restrict__ acc1) {
    __shared__ float sx[4][36 * XSF];   // x ring of 4 (43.8 KB)
    __shared__ float srm[2][34 * RSF];  // rowmax ring of 2 (18.5 KB)

    // XCD-chunked swizzle
    int cpx = gridDim.x >> 3;
    int hwb = blockIdx.x;
    int bx  = (hwb & 7) * cpx + (hwb >> 3);

    int t   = bx >> 8;                 // tensor select (0 when grid=256)
    int bt  = bx & 255;
    int w0  = (bt & 3) * 64;
    int h0  = ((bt >> 2) & 7) * 32;
    int gd0 = ((bt >> 5) & 3) * CD;
    int b   = (bt >> 7) & 1;

    const float* xin  = t ? in1  : in0;
    float*       xout = t ? out1 : out0;
    const float* oth  = t ? oth1 : oth0;
    double*      accp = t ? acc1 : acc0;

    int tid = threadIdx.x;
    int r   = tid >> 3;   // 0..31 output row
    int k   = tid & 7;    // 0..7  8-col job

    const float* xb  = xin + b * (D * HW);
    float*       ob  = xout ? (xout + b * (D * HW)) : nullptr;
    const float* otb = oth + b * (D * HW);

    const float4 INF4  = make_float4( INFINITY,  INFINITY,  INFINITY,  INFINITY);
    const float4 NINF4 = make_float4(-INFINITY, -INFINITY, -INFINITY, -INFINITY);

    // staging map: 648 quads (36 rows x 18), 3 rounds of 256
    int j1 = tid + 256, j2 = tid + 512;
    int sr0 = tid / 18, sq0 = tid - sr0 * 18;
    int sr1 = j1 / 18,  sq1 = j1 - sr1 * 18;
    int sr2 = j2 / 18,  sq2 = j2 - sr2 * 18;
    bool has2 = (j2 < 648);

    float4 Pa, Pb, Pc;   // pending plane
    auto issue = [&](int p) {
        if (p < 0 || p >= D) { Pa = Pb = Pc = INF4; return; }
        const float* pl = xb + p * HW;
        auto f = [&](int row, int qd) -> float4 {
            int gh = h0 - 2 + row;
            int gw = w0 - 4 + 4 * qd;
            if ((unsigned)gh < (unsigned)H && (unsigned)gw < (unsigned)W)
                return *(const float4*)(pl + gh * W + gw);
            return INF4;
        };
        Pa = f(sr0, sq0);
        Pb = f(sr1, sq1);
        Pc = has2 ? f(sr2, sq2) : INF4;
    };
    auto commitv = [&](int p, float4 va, float4 vb, float4 vc) {
        float* dst = sx[(p + 4) & 3];
        *(float4*)&dst[sr0 * XSF + 4 * sq0] = va;
        *(float4*)&dst[sr1 * XSF + 4 * sq1] = vb;
        if (has2) *(float4*)&dst[sr2 * XSF + 4 * sq2] = vc;
    };

    // Prologue: planes gd0-2..gd0 resident; x[gd0+1] pending.
    issue(gd0 - 2); commitv(gd0 - 2, Pa, Pb, Pc);
    issue(gd0 - 1); commitv(gd0 - 1, Pa, Pb, Pc);
    issue(gd0);     commitv(gd0,     Pa, Pb, Pc);
    issue(gd0 + 1);
    __syncthreads();

    float4 h1lo=NINF4, h1hi=NINF4, h2lo=NINF4, h2hi=NINF4;  // hw9 D-ring
    float4 p1lo=NINF4, p1hi=NINF4, p2lo=NINF4, p2hi=NINF4;  // mp centers
    float4 rmplo=NINF4, rmphi=NINF4;                        // reg rowmax of s-1
    float4 xplo=INF4, xphi=INF4;                            // x center of s-2
    double s0 = 0.0, s1 = 0.0;

    for (int s = gd0 - 1; s <= gd0 + CD + 1; ++s) {
        // ---- staging: commit x[s+2] (captured), issue x[s+3] ----
        float4 Ta = Pa, Tb = Pb, Tc = Pc;
        if (s + 3 <= gd0 + CD + 1) issue(s + 3);
        if (s + 2 <= gd0 + CD + 1) commitv(s + 2, Ta, Tb, Tc);

        // ---- B(s): mp row r+1 in regs, rowmax -> srm[s&1] ----
        bool sv = (s >= 0 && s < D && s <= gd0 + CD);
        float4 lo = NINF4, hi = NINF4, rmlo = NINF4, rmhi = NINF4;
        if (sv) {
            const float* xq = sx[(s + 4) & 3];
            const float* xm = sx[(s + 3) & 3];
            const float* xp = sx[(s + 5) & 3];
            {
                const float* rc  = &xq[(r + 2) * XSF + 8 * k];
                const float* ru  = &xq[(r + 1) * XSF + 8 * k];
                const float* rd  = &xq[(r + 3) * XSF + 8 * k];
                const float* rm_ = &xm[(r + 2) * XSF + 8 * k];
                const float* rp_ = &xp[(r + 2) * XSF + 8 * k];
                float4 X0 = *(const float4*)rc,        X1 = *(const float4*)(rc + 4),
                       X2 = *(const float4*)(rc + 8),  X3 = *(const float4*)(rc + 12);
                float4 U1 = *(const float4*)(ru + 4),  U2 = *(const float4*)(ru + 8);
                float4 Dn1= *(const float4*)(rd + 4),  Dn2= *(const float4*)(rd + 8);
                float4 M1 = *(const float4*)(rm_ + 4), M2 = *(const float4*)(rm_ + 8);
                float4 P1 = *(const float4*)(rp_ + 4), P2 = *(const float4*)(rp_ + 8);
                lo = vmin4(vmin4(sh3(X0, X1), X1), sh1(X1, X2));
                lo = vmin4(lo, vmin4(vmin4(U1, Dn1), vmin4(M1, P1)));
                hi = vmin4(vmin4(sh3(X1, X2), X2), sh1(X2, X3));
                hi = vmin4(hi, vmin4(vmin4(U2, Dn2), vmin4(M2, P2)));
                float eL = __shfl_up(hi.w, 1);
                float eR = __shfl_down(lo.x, 1);
                if (k == 0) {
                    eL = -INFINITY;
                    if (w0 > 0) {
                        float w3 = fminf(fminf(X0.z, X0.w), X1.x);
                        eL = fminf(fminf(w3, fminf(ru[3], rd[3])),
                                   fminf(rm_[3], rp_[3]));
                    }
                }
                if (k == 7) {
                    eR = -INFINITY;
                    if (w0 + 64 < W) {
                        float w3 = fminf(fminf(X2.w, X3.x), X3.y);
                        eR = fminf(fminf(w3, fminf(ru[12], rd[12])),
                                   fminf(rm_[12], rp_[12]));
                    }
                }
                rmlo = vmax4(vmax4(make_float4(eL, lo.x, lo.y, lo.z), lo),
                             make_float4(lo.y, lo.z, lo.w, hi.x));
                rmhi = vmax4(vmax4(make_float4(lo.w, hi.x, hi.y, hi.z), hi),
                             make_float4(hi.y, hi.z, hi.w, eR));
                float* rw = &srm[s & 1][(r + 1) * RSF + 8 * k];
                *(float4*)rw       = rmlo;
                *(float4*)(rw + 4) = rmhi;
            }
            if (tid < 16) {    // halo rows 0 and 33, fully in-thread
                int mr2 = (tid >> 3) ? 33 : 0;
                int k2  = tid & 7;
                int gh2 = h0 - 1 + mr2;
                float4 hlo = NINF4, hhi = NINF4;
                if ((unsigned)gh2 < (unsigned)H) {
                    int xr2 = mr2 + 1;
                    const float* rc  = &xq[xr2 * XSF + 8 * k2];
                    const float* ru  = &xq[(xr2 - 1) * XSF + 8 * k2];
                    const float* rd  = &xq[(xr2 + 1) * XSF + 8 * k2];
                    const float* rm_ = &xm[xr2 * XSF + 8 * k2];
                    const float* rp_ = &xp[xr2 * XSF + 8 * k2];
                    float4 X0 = *(const float4*)rc,        X1 = *(const float4*)(rc + 4),
                           X2 = *(const float4*)(rc + 8),  X3 = *(const float4*)(rc + 12);
                    float4 U1 = *(const float4*)(ru + 4),  U2 = *(const float4*)(ru + 8);
                    float4 Dn1= *(const float4*)(rd + 4),  Dn2= *(const float4*)(rd + 8);
                    float4 M1 = *(const float4*)(rm_ + 4), M2 = *(const float4*)(rm_ + 8);
                    float4 P1 = *(const float4*)(rp_ + 4), P2 = *(const float4*)(rp_ + 8);
                    float4 l2 = vmin4(vmin4(sh3(X0, X1), X1), sh1(X1, X2));
                    l2 = vmin4(l2, vmin4(vmin4(U1, Dn1), vmin4(M1, P1)));
                    float4 g2 = vmin4(vmin4(sh3(X1, X2), X2), sh1(X2, X3));
                    g2 = vmin4(g2, vmin4(vmin4(U2, Dn2), vmin4(M2, P2)));
                    float eL2 = -INFINITY, eR2 = -INFINITY;
                    if (w0 + 8 * k2 - 1 >= 0) {
                        float w3 = fminf(fminf(X0.z, X0.w), X1.x);
                        eL2 = fminf(fminf(w3, fminf(ru[3], rd[3])),
                                    fminf(rm_[3], rp_[3]));
                    }
                    if (w0 + 8 * k2 + 8 < W) {
                        float w3 = fminf(fminf(X2.w, X3.x), X3.y);
                        eR2 = fminf(fminf(w3, fminf(ru[12], rd[12])),
                                    fminf(rm_[12], rp_[12]));
                    }
                    hlo = vmax4(vmax4(make_float4(eL2, l2.x, l2.y, l2.z), l2),
                                make_float4(l2.y, l2.z, l2.w, g2.x));
                    hhi = vmax4(vmax4(make_float4(l2.w, g2.x, g2.y, g2.z), g2),
                                make_float4(g2.y, g2.z, g2.w, eR2));
                }
                float* hw = &srm[s & 1][mr2 * RSF + 8 * k2];
                *(float4*)hw       = hlo;
                *(float4*)(hw + 4) = hhi;
            }
        }

        // ---- xc: x center of plane s-1 (slot (s+3)&3; commit wrote (s+2)&3) ----
        int dm = s - 1;
        float4 xclo = INF4, xchi = INF4;
        if (dm >= gd0 && dm <= gd0 + CD - 1) {
            const float* xd = sx[(dm + 4) & 3];
            xclo = *(const float4*)&xd[(r + 2) * XSF + 8 * k + 4];
            xchi = *(const float4*)&xd[(r + 2) * XSF + 8 * k + 8];
        }

        // ---- H(s-1): hw9 of plane s-1 (rm written last segment + reg row) ----
        float4 hclo = NINF4, hchi = NINF4;
        if (s >= gd0 && dm >= 0 && dm < D) {
            const float* m = srm[dm & 1];
            float4 a0 = *(const float4*)&m[r * RSF + 8 * k];
            float4 a1 = *(const float4*)&m[r * RSF + 8 * k + 4];
            float4 b0 = *(const float4*)&m[(r + 2) * RSF + 8 * k];
            float4 b1 = *(const float4*)&m[(r + 2) * RSF + 8 * k + 4];
            hclo = vmax4(vmax4(a0, rmplo), b0);
            hchi = vmax4(vmax4(a1, rmphi), b1);
        }

        // ---- C(s-2): output d = s-2 (registers only + global) ----
        int d = s - 2;
        if (d >= gd0 && d <= gd0 + CD - 1) {
            float4 mxlo = vmax4(h2lo, vmax4(h1lo, hclo));
            float4 mxhi = vmax4(h2hi, vmax4(h1hi, hchi));
            float4 rlo, rhi;
            rlo.x = fmaxf(xplo.x - (mxlo.x - p2lo.x), 0.0f);
            rlo.y = fmaxf(xplo.y - (mxlo.y - p2lo.y), 0.0f);
            rlo.z = fmaxf(xplo.z - (mxlo.z - p2lo.z), 0.0f);
            rlo.w = fmaxf(xplo.w - (mxlo.w - p2lo.w), 0.0f);
            rhi.x = fmaxf(xphi.x - (mxhi.x - p2hi.x), 0.0f);
            rhi.y = fmaxf(xphi.y - (mxhi.y - p2hi.y), 0.0f);
            rhi.z = fmaxf(xphi.z - (mxhi.z - p2hi.z), 0.0f);
            rhi.w = fmaxf(xphi.w - (mxhi.w - p2hi.w), 0.0f);
            long off = (long)d * HW + (h0 + r) * W + (w0 + 8 * k);
            if constexpr (FINAL) {
                float4 o1 = *(const float4*)(otb + off);
                float4 o2 = *(const float4*)(otb + off + 4);
                s0 += (double)(rlo.x * o1.x) + (double)(rlo.y * o1.y)
                    + (double)(rlo.z * o1.z) + (double)(rlo.w * o1.w)
                    + (double)(rhi.x * o2.x) + (double)(rhi.y * o2.y)
                    + (double)(rhi.z * o2.z) + (double)(rhi.w * o2.w);
                s1 += (double)rlo.x + (double)rlo.y + (double)rlo.z + (double)rlo.w
                    + (double)rhi.x + (double)rhi.y + (double)rhi.z + (double)rhi.w;
            } else {
                *(float4*)(ob + off)     = rlo;
                *(float4*)(ob + off + 4) = rhi;
            }
        }

        // ---- shifts ----
        h2lo = h1lo; h2hi = h1hi; h1lo = hclo; h1hi = hchi;
        p2lo = p1lo; p2hi = p1hi; p1lo = lo;   p1hi = hi;
        rmplo = rmlo; rmphi = rmhi;
        xplo = xclo;  xphi = xchi;

        lds_barrier();   // the ONLY barrier per segment (LDS drain only)
    }

    if constexpr (FINAL) {
        for (int off = 32; off > 0; off >>= 1) {
            s0 += __shfl_down(s0, off, 64);
            s1 += __shfl_down(s1, off, 64);
        }
        if ((tid & 63) == 0) {
            atomicAdd(&accp[0], s0);
            atomicAdd(&accp[1], s1);
        }
    }
}

__global__ void final_kernel(const double* __restrict__ acc, float* __restrict__ out) {
    double clrecall = (acc[0] + 1e-12) / (acc[1] + 1e-12);
    double clacc    = (acc[2] + 1e-12) / (acc[3] + 1e-12);
    double cldice   = 2.0 * clrecall * clacc / (clrecall + clacc + 1e-12);
    out[0] = (float)(1.0 - cldice);
}

extern "C" void kernel_launch(void* const* d_in, const int* in_sizes, int n_in,
                              void* d_out, int out_size, void* d_ws, size_t ws_size,
                              hipStream_t stream) {
    const float* logits = (const float*)d_in[0];
    const float* target = (const float*)d_in[1];
    const float* mask   = (const float*)d_in[2];
    float* out = (float*)d_out;

    float* pred = (float*)d_ws;
    float* tgt  = pred + NV;
    float* A0   = tgt + NV;
    float* B0   = A0 + NV;

    bool big = ws_size >= (size_t)6 * NV * 4 + 64;
    float* A1   = big ? (B0 + NV) : A0;
    float* B1   = big ? (A1 + NV) : B0;
    double* acc = big ? (double*)(B1 + NV) : (double*)(B0 + NV);

    hipMemsetAsync(acc, 0, 4 * sizeof(double), stream);

    dim3 blk(256);
    prep_kernel<<<dim3(NV / 1024), blk, 0, stream>>>(logits, target, mask, pred, tgt);

    if (big) {
        dim3 g(512);   // 2 tensors x 256 blocks; 2 blocks/CU, all resident
        skel_iter_kernel<false><<<g, blk, 0, stream>>>(tgt, A0, pred, acc, pred, A1, tgt, acc + 2);
        skel_iter_kernel<false><<<g, blk, 0, stream>>>(A0, B0, pred, acc, A1, B1, tgt, acc + 2);
        skel_iter_kernel<false><<<g, blk, 0, stream>>>(B0, A0, pred, acc, B1, A1, tgt, acc + 2);
        skel_iter_kernel<false><<<g, blk, 0, stream>>>(A0, B0, pred, acc, A1, B1, tgt, acc + 2);
        skel_iter_kernel<true ><<<g, blk, 0, stream>>>(B0, nullptr, pred, acc, B1, nullptr, tgt, acc + 2);
    } else {
        dim3 g(256);   // sequential fallback (t = 0 always)
        skel_iter_kernel<false><<<g, blk, 0, stream>>>(tgt, A0, pred, acc, tgt, A0, pred, acc);
        skel_iter_kernel<false><<<g, blk, 0, stream>>>(A0, B0, pred, acc, A0, B0, pred, acc);
        skel_iter_kernel<false><<<g, blk, 0, stream>>>(B0, A0, pred, acc, B0, A0, pred, acc);
        skel_iter_kernel<false><<<g, blk, 0, stream>>>(A0, B0, pred, acc, A0, B0, pred, acc);
        skel_iter_kernel<true ><<<g, blk, 0, stream>>>(B0, nullptr, pred, acc, B0, nullptr, pred, acc);
        skel_iter_kernel<false><<<g, blk, 0, stream>>>(pred, A0, tgt, acc + 2, pred, A0, tgt, acc + 2);
        skel_iter_kernel<false><<<g, blk, 0, stream>>>(A0, B0, tgt, acc + 2, A0, B0, tgt, acc + 2);
        skel_iter_kernel<false><<<g, blk, 0, stream>>>(B0, A0, tgt, acc + 2, B0, A0, tgt, acc + 2);
        skel_iter_kernel<false><<<g, blk, 0, stream>>>(A0, B0, tgt, acc + 2, A0, B0, tgt, acc + 2);
        skel_iter_kernel<true ><<<g, blk, 0, stream>>>(B0, nullptr, tgt, acc + 2, B0, nullptr, tgt, acc + 2);
    }

    final_kernel<<<1, 1, 0, stream>>>(acc, out);
}

// Round 16
// 282.743 us; speedup vs baseline: 1.2775x; 1.1107x over previous
//
#include <hip/hip_runtime.h>
#include <math.h>

// SoftclDiceLoss on (B,C,D,H,W) = (2,1,64,256,256) float32.
// R16 = R15 (314us: CD=16, grid 512, x ring-4, srm ring-2, ONE barrier/seg,
// no-vmcnt-drain barrier) + two LDS-instruction cuts:
//  (1) xc-dedup: x-center of plane s-1 == M1/M2 already read by B(s) (same
//      address, same segment). Fallback LDS read only when !sv (s==64 case).
//  (2) staging via global_load_lds (DMA, no ds_write, no VGPR round-trip).
//      Layout: linear quads j=row*19+q (XSF=76 kept -> bank patterns
//      unchanged); hole lanes (q==18) and OOB lanes source a +INF dummy in
//      d_ws. 12 chunks of 64 quads -> 3 gload_lds per wave per plane.
//      Depth-1 issue (plane s+2 during segment s; ring-4 WAR audit: old
//      tenant plane s-2 last read pre-barrier(s-1)). Drain: vmcnt(0) for
//      s<=gd0+1 (no stores yet), else vmcnt(2) (youngest-2 = this segment's
//      2 C-stores / FINAL o-loads; in-order vmcnt => all gloads retired).

constexpr int Bn = 2;
constexpr int D  = 64;
constexpr int H  = 256;
constexpr int W  = 256;
constexpr int HW = H * W;           // 65536
constexpr int NV = Bn * D * H * W;  // 8388608

constexpr int CD  = 16;             // D-chunk per block
constexpr int XSF = 76;             // x LDS row stride (19 quads, odd)
constexpr int XPQ = 768;            // padded plane size in quads (12 x 64)
constexpr int RSF = 68;             // rowmax LDS row stride (17 quads, odd)

__device__ __forceinline__ void seg_barrier_v0() {
    asm volatile("s_waitcnt vmcnt(0) lgkmcnt(0)" ::: "memory");
    __builtin_amdgcn_s_barrier();
    asm volatile("" ::: "memory");
}
__device__ __forceinline__ void seg_barrier_v2() {
    asm volatile("s_waitcnt vmcnt(2) lgkmcnt(0)" ::: "memory");
    __builtin_amdgcn_s_barrier();
    asm volatile("" ::: "memory");
}

__device__ __forceinline__ float4 vmin4(float4 a, float4 b) {
    return make_float4(fminf(a.x,b.x), fminf(a.y,b.y), fminf(a.z,b.z), fminf(a.w,b.w));
}
__device__ __forceinline__ float4 vmax4(float4 a, float4 b) {
    return make_float4(fmaxf(a.x,b.x), fmaxf(a.y,b.y), fmaxf(a.z,b.z), fmaxf(a.w,b.w));
}
__device__ __forceinline__ float4 sh1(float4 a, float4 b) { return make_float4(a.y,a.z,a.w,b.x); }
__device__ __forceinline__ float4 sh3(float4 a, float4 b) { return make_float4(a.w,b.x,b.y,b.z); }

__global__ __launch_bounds__(256) void prep_kernel(const float* __restrict__ logits,
                                                   const float* __restrict__ target,
                                                   const float* __restrict__ mask,
                                                   float* __restrict__ pred,
                                                   float* __restrict__ tgt,
                                                   float* __restrict__ infbuf) {
    int i = (blockIdx.x * 256 + threadIdx.x) * 4;
    float4 lg = *(const float4*)(logits + i);
    float4 tg = *(const float4*)(target + i);
    float4 mk = *(const float4*)(mask + i);
    float4 p, t;
    p.x = (1.0f/(1.0f+expf(-lg.x)))*mk.x;  t.x = tg.x*mk.x;
    p.y = (1.0f/(1.0f+expf(-lg.y)))*mk.y;  t.y = tg.y*mk.y;
    p.z = (1.0f/(1.0f+expf(-lg.z)))*mk.z;  t.z = tg.z*mk.z;
    p.w = (1.0f/(1.0f+expf(-lg.w)))*mk.w;  t.w = tg.w*mk.w;
    *(float4*)(pred + i) = p;
    *(float4*)(tgt + i)  = t;
    if (blockIdx.x == 0 && threadIdx.x == 0) {
        *(float4*)infbuf = make_float4(INFINITY, INFINITY, INFINITY, INFINITY);
    }
}

template <bool FINAL>
__global__ __launch_bounds__(256) void skel_iter_kernel(
        const float* __restrict__ in0, float* __restrict__ out0,
        const float* __restrict__ oth0, double* __restrict__ acc0,
        const float* __restrict__ in1, float* __restrict__ out1,
        const float* __restrict__ oth1, double* __restrict__ acc1,
        const float* __restrict__ infbuf) {
    __shared__ float sx[4][XPQ * 4];    // x ring of 4, padded planes (48 KB)
    __shared__ float srm[2][34 * RSF];  // rowmax ring of 2 (18.5 KB)

    // XCD-chunked swizzle
    int cpx = gridDim.x >> 3;
    int hwb = blockIdx.x;
    int bx  = (hwb & 7) * cpx + (hwb >> 3);

    int t   = bx >> 8;                 // tensor select (0 when grid=256)
    int bt  = bx & 255;
    int w0  = (bt & 3) * 64;
    int h0  = ((bt >> 2) & 7) * 32;
    int gd0 = ((bt >> 5) & 3) * CD;
    int b   = (bt >> 7) & 1;

    const float* xin  = t ? in1  : in0;
    float*       xout = t ? out1 : out0;
    const float* oth  = t ? oth1 : oth0;
    double*      accp = t ? acc1 : acc0;

    int tid  = threadIdx.x;
    int r    = tid >> 3;   // 0..31 output row
    int k    = tid & 7;    // 0..7  8-col job
    int wv   = tid >> 6;   // wave id 0..3
    int lane = tid & 63;

    const float* xb  = xin + b * (D * HW);
    float*       ob  = xout ? (xout + b * (D * HW)) : nullptr;
    const float* otb = oth + b * (D * HW);

    const float4 INF4  = make_float4( INFINITY,  INFINITY,  INFINITY,  INFINITY);
    const float4 NINF4 = make_float4(-INFINITY, -INFINITY, -INFINITY, -INFINITY);

    // Per-lane gload source precompute: chunk c = wv + 4*i, quad j = 64c+lane,
    // row = j/19, q = j%19. Holes (q==18), rows>=36, and OOB -> infbuf.
    int  offe[3];
    bool okl[3];
    for (int i = 0; i < 3; ++i) {
        int c = wv + 4 * i;
        int j = 64 * c + lane;
        int row = j / 19;
        int q = j - 19 * row;
        int gh = h0 - 2 + row;
        int gw = w0 - 4 + 4 * q;
        okl[i] = (q < 18) && (row < 36) &&
                 ((unsigned)gh < (unsigned)H) && ((unsigned)gw < (unsigned)W);
        offe[i] = gh * W + gw;
    }

    auto issue_g = [&](int p) {
        bool pok = (p >= 0 && p < D);
        const float* pbase = xb + (long)p * HW;
        float* slot = sx[(p + 4) & 3];
        #pragma unroll
        for (int i = 0; i < 3; ++i) {
            const float* src = (pok && okl[i]) ? (pbase + offe[i]) : infbuf;
            float* dst = slot + (wv + 4 * i) * 256;   // 64 quads = 256 floats
            __builtin_amdgcn_global_load_lds(
                (const __attribute__((address_space(1))) void*)src,
                (__attribute__((address_space(3))) void*)dst, 16, 0, 0);
        }
    };

    // Prologue: planes gd0-2..gd0+1 staged via DMA; full drain.
    issue_g(gd0 - 2); issue_g(gd0 - 1); issue_g(gd0); issue_g(gd0 + 1);
    __syncthreads();

    float4 h1lo=NINF4, h1hi=NINF4, h2lo=NINF4, h2hi=NINF4;  // hw9 D-ring
    float4 p1lo=NINF4, p1hi=NINF4, p2lo=NINF4, p2hi=NINF4;  // mp centers
    float4 rmplo=NINF4, rmphi=NINF4;                        // reg rowmax of s-1
    float4 xplo=INF4, xphi=INF4;                            // x center of s-2
    double s0 = 0.0, s1 = 0.0;

    for (int s = gd0 - 1; s <= gd0 + CD + 1; ++s) {
        // ---- staging: DMA plane s+2 into slot (s+2)&3 (depth-1) ----
        if (s >= gd0 && s + 2 <= gd0 + CD + 1) issue_g(s + 2);
        asm volatile("" ::: "memory");   // pin gloads before later VMEM ops

        // ---- B(s): mp row r+1 in regs, rowmax -> srm[s&1] ----
        bool sv = (s >= 0 && s < D && s <= gd0 + CD);
        float4 lo = NINF4, hi = NINF4, rmlo = NINF4, rmhi = NINF4;
        float4 vM1 = INF4, vM2 = INF4;   // saved M1/M2 (== xc of plane s-1)
        if (sv) {
            const float* xq = sx[(s + 4) & 3];
            const float* xm = sx[(s + 3) & 3];
            const float* xp = sx[(s + 5) & 3];
            {
                const float* rc  = &xq[(r + 2) * XSF + 8 * k];
                const float* ru  = &xq[(r + 1) * XSF + 8 * k];
                const float* rd  = &xq[(r + 3) * XSF + 8 * k];
                const float* rm_ = &xm[(r + 2) * XSF + 8 * k];
                const float* rp_ = &xp[(r + 2) * XSF + 8 * k];
                float4 X0 = *(const float4*)rc,        X1 = *(const float4*)(rc + 4),
                       X2 = *(const float4*)(rc + 8),  X3 = *(const float4*)(rc + 12);
                float4 U1 = *(const float4*)(ru + 4),  U2 = *(const float4*)(ru + 8);
                float4 Dn1= *(const float4*)(rd + 4),  Dn2= *(const float4*)(rd + 8);
                float4 M1 = *(const float4*)(rm_ + 4), M2 = *(const float4*)(rm_ + 8);
                float4 P1 = *(const float4*)(rp_ + 4), P2 = *(const float4*)(rp_ + 8);
                vM1 = M1; vM2 = M2;
                lo = vmin4(vmin4(sh3(X0, X1), X1), sh1(X1, X2));
                lo = vmin4(lo, vmin4(vmin4(U1, Dn1), vmin4(M1, P1)));
                hi = vmin4(vmin4(sh3(X1, X2), X2), sh1(X2, X3));
                hi = vmin4(hi, vmin4(vmin4(U2, Dn2), vmin4(M2, P2)));
                float eL = __shfl_up(hi.w, 1);
                float eR = __shfl_down(lo.x, 1);
                if (k == 0) {
                    eL = -INFINITY;
                    if (w0 > 0) {
                        float w3 = fminf(fminf(X0.z, X0.w), X1.x);
                        eL = fminf(fminf(w3, fminf(ru[3], rd[3])),
                                   fminf(rm_[3], rp_[3]));
                    }
                }
                if (k == 7) {
                    eR = -INFINITY;
                    if (w0 + 64 < W) {
                        float w3 = fminf(fminf(X2.w, X3.x), X3.y);
                        eR = fminf(fminf(w3, fminf(ru[12], rd[12])),
                                   fminf(rm_[12], rp_[12]));
                    }
                }
                rmlo = vmax4(vmax4(make_float4(eL, lo.x, lo.y, lo.z), lo),
                             make_float4(lo.y, lo.z, lo.w, hi.x));
                rmhi = vmax4(vmax4(make_float4(lo.w, hi.x, hi.y, hi.z), hi),
                             make_float4(hi.y, hi.z, hi.w, eR));
                float* rw = &srm[s & 1][(r + 1) * RSF + 8 * k];
                *(float4*)rw       = rmlo;
                *(float4*)(rw + 4) = rmhi;
            }
            if (tid < 16) {    // halo rows 0 and 33, fully in-thread
                int mr2 = (tid >> 3) ? 33 : 0;
                int k2  = tid & 7;
                int gh2 = h0 - 1 + mr2;
                float4 hlo = NINF4, hhi = NINF4;
                if ((unsigned)gh2 < (unsigned)H) {
                    int xr2 = mr2 + 1;
                    const float* rc  = &xq[xr2 * XSF + 8 * k2];
                    const float* ru  = &xq[(xr2 - 1) * XSF + 8 * k2];
                    const float* rd  = &xq[(xr2 + 1) * XSF + 8 * k2];
                    const float* rm_ = &xm[xr2 * XSF + 8 * k2];
                    const float* rp_ = &xp[xr2 * XSF + 8 * k2];
                    float4 X0 = *(const float4*)rc,        X1 = *(const float4*)(rc + 4),
                           X2 = *(const float4*)(rc + 8),  X3 = *(const float4*)(rc + 12);
                    float4 U1 = *(const float4*)(ru + 4),  U2 = *(const float4*)(ru + 8);
                    float4 Dn1= *(const float4*)(rd + 4),  Dn2= *(const float4*)(rd + 8);
                    float4 M1 = *(const float4*)(rm_ + 4), M2 = *(const float4*)(rm_ + 8);
                    float4 P1 = *(const float4*)(rp_ + 4), P2 = *(const float4*)(rp_ + 8);
                    float4 l2 = vmin4(vmin4(sh3(X0, X1), X1), sh1(X1, X2));
                    l2 = vmin4(l2, vmin4(vmin4(U1, Dn1), vmin4(M1, P1)));
                    float4 g2 = vmin4(vmin4(sh3(X1, X2), X2), sh1(X2, X3));
                    g2 = vmin4(g2, vmin4(vmin4(U2, Dn2), vmin4(M2, P2)));
                    float eL2 = -INFINITY, eR2 = -INFINITY;
                    if (w0 + 8 * k2 - 1 >= 0) {
                        float w3 = fminf(fminf(X0.z, X0.w), X1.x);
                        eL2 = fminf(fminf(w3, fminf(ru[3], rd[3])),
                                    fminf(rm_[3], rp_[3]));
                    }
                    if (w0 + 8 * k2 + 8 < W) {
                        float w3 = fminf(fminf(X2.w, X3.x), X3.y);
                        eR2 = fminf(fminf(w3, fminf(ru[12], rd[12])),
                                    fminf(rm_[12], rp_[12]));
                    }
                    hlo = vmax4(vmax4(make_float4(eL2, l2.x, l2.y, l2.z), l2),
                                make_float4(l2.y, l2.z, l2.w, g2.x));
                    hhi = vmax4(vmax4(make_float4(l2.w, g2.x, g2.y, g2.z), g2),
                                make_float4(g2.y, g2.z, g2.w, eR2));
                }
                float* hw = &srm[s & 1][mr2 * RSF + 8 * k2];
                *(float4*)hw       = hlo;
                *(float4*)(hw + 4) = hhi;
            }
        }

        // ---- xc: x center of plane s-1 == vM1/vM2 (xc-dedup) ----
        int dm = s - 1;
        float4 xclo = INF4, xchi = INF4;
        if (dm >= gd0 && dm <= gd0 + CD - 1) {
            if (sv) { xclo = vM1; xchi = vM2; }
            else {   // only the s == gd0+CD == D case (last chunk)
                const float* xd = sx[(dm + 4) & 3];
                xclo = *(const float4*)&xd[(r + 2) * XSF + 8 * k + 4];
                xchi = *(const float4*)&xd[(r + 2) * XSF + 8 * k + 8];
            }
        }

        // ---- H(s-1): hw9 of plane s-1 (rm written last segment + reg row) ----
        float4 hclo = NINF4, hchi = NINF4;
        if (s >= gd0 && dm >= 0 && dm < D) {
            const float* m = srm[dm & 1];
            float4 a0 = *(const float4*)&m[r * RSF + 8 * k];
            float4 a1 = *(const float4*)&m[r * RSF + 8 * k + 4];
            float4 b0 = *(const float4*)&m[(r + 2) * RSF + 8 * k];
            float4 b1 = *(const float4*)&m[(r + 2) * RSF + 8 * k + 4];
            hclo = vmax4(vmax4(a0, rmplo), b0);
            hchi = vmax4(vmax4(a1, rmphi), b1);
        }

        // ---- C(s-2): output d = s-2 (registers only + global) ----
        int d = s - 2;
        if (d >= gd0 && d <= gd0 + CD - 1) {
            float4 mxlo = vmax4(h2lo, vmax4(h1lo, hclo));
            float4 mxhi = vmax4(h2hi, vmax4(h1hi, hchi));
            float4 rlo, rhi;
            rlo.x = fmaxf(xplo.x - (mxlo.x - p2lo.x), 0.0f);
            rlo.y = fmaxf(xplo.y - (mxlo.y - p2lo.y), 0.0f);
            rlo.z = fmaxf(xplo.z - (mxlo.z - p2lo.z), 0.0f);
            rlo.w = fmaxf(xplo.w - (mxlo.w - p2lo.w), 0.0f);
            rhi.x = fmaxf(xphi.x - (mxhi.x - p2hi.x), 0.0f);
            rhi.y = fmaxf(xphi.y - (mxhi.y - p2hi.y), 0.0f);
            rhi.z = fmaxf(xphi.z - (mxhi.z - p2hi.z), 0.0f);
            rhi.w = fmaxf(xphi.w - (mxhi.w - p2hi.w), 0.0f);
            long off = (long)d * HW + (h0 + r) * W + (w0 + 8 * k);
            if constexpr (FINAL) {
                float4 o1 = *(const float4*)(otb + off);
                float4 o2 = *(const float4*)(otb + off + 4);
                s0 += (double)(rlo.x * o1.x) + (double)(rlo.y * o1.y)
                    + (double)(rlo.z * o1.z) + (double)(rlo.w * o1.w)
                    + (double)(rhi.x * o2.x) + (double)(rhi.y * o2.y)
                    + (double)(rhi.z * o2.z) + (double)(rhi.w * o2.w);
                s1 += (double)rlo.x + (double)rlo.y + (double)rlo.z + (double)rlo.w
                    + (double)rhi.x + (double)rhi.y + (double)rhi.z + (double)rhi.w;
            } else {
                *(float4*)(ob + off)     = rlo;
                *(float4*)(ob + off + 4) = rhi;
            }
        }

        // ---- shifts ----
        h2lo = h1lo; h2hi = h1hi; h1lo = hclo; h1hi = hchi;
        p2lo = p1lo; p2hi = p1hi; p1lo = lo;   p1hi = hi;
        rmplo = rmlo; rmphi = rmhi;
        xplo = xclo;  xphi = xchi;

        // ---- barrier: drain gloads (v0 while no stores exist, else v2) ----
        if (s <= gd0 + 1) seg_barrier_v0();
        else              seg_barrier_v2();
    }

    if constexpr (FINAL) {
        for (int off = 32; off > 0; off >>= 1) {
            s0 += __shfl_down(s0, off, 64);
            s1 += __shfl_down(s1, off, 64);
        }
        if ((tid & 63) == 0) {
            atomicAdd(&accp[0], s0);
            atomicAdd(&accp[1], s1);
        }
    }
}

__global__ void final_kernel(const double* __restrict__ acc, float* __restrict__ out) {
    double clrecall = (acc[0] + 1e-12) / (acc[1] + 1e-12);
    double clacc    = (acc[2] + 1e-12) / (acc[3] + 1e-12);
    double cldice   = 2.0 * clrecall * clacc / (clrecall + clacc + 1e-12);
    out[0] = (float)(1.0 - cldice);
}

extern "C" void kernel_launch(void* const* d_in, const int* in_sizes, int n_in,
                              void* d_out, int out_size, void* d_ws, size_t ws_size,
                              hipStream_t stream) {
    const float* logits = (const float*)d_in[0];
    const float* target = (const float*)d_in[1];
    const float* mask   = (const float*)d_in[2];
    float* out = (float*)d_out;

    float* pred = (float*)d_ws;
    float* tgt  = pred + NV;
    float* A0   = tgt + NV;
    float* B0   = A0 + NV;

    bool big = ws_size >= (size_t)6 * NV * 4 + 64;
    float* A1    = big ? (B0 + NV) : A0;
    float* B1    = big ? (A1 + NV) : B0;
    double* acc  = big ? (double*)(B1 + NV) : (double*)(B0 + NV);
    float* infb  = (float*)(acc + 4);   // 16B +INF dummy for OOB gload lanes

    hipMemsetAsync(acc, 0, 4 * sizeof(double), stream);

    dim3 blk(256);
    prep_kernel<<<dim3(NV / 1024), blk, 0, stream>>>(logits, target, mask, pred, tgt, infb);

    if (big) {
        dim3 g(512);   // 2 tensors x 256 blocks; 2 blocks/CU, all resident
        skel_iter_kernel<false><<<g, blk, 0, stream>>>(tgt, A0, pred, acc, pred, A1, tgt, acc + 2, infb);
        skel_iter_kernel<false><<<g, blk, 0, stream>>>(A0, B0, pred, acc, A1, B1, tgt, acc + 2, infb);
        skel_iter_kernel<false><<<g, blk, 0, stream>>>(B0, A0, pred, acc, B1, A1, tgt, acc + 2, infb);
        skel_iter_kernel<false><<<g, blk, 0, stream>>>(A0, B0, pred, acc, A1, B1, tgt, acc + 2, infb);
        skel_iter_kernel<true ><<<g, blk, 0, stream>>>(B0, nullptr, pred, acc, B1, nullptr, tgt, acc + 2, infb);
    } else {
        dim3 g(256);   // sequential fallback (t = 0 always)
        skel_iter_kernel<false><<<g, blk, 0, stream>>>(tgt, A0, pred, acc, tgt, A0, pred, acc, infb);
        skel_iter_kernel<false><<<g, blk, 0, stream>>>(A0, B0, pred, acc, A0, B0, pred, acc, infb);
        skel_iter_kernel<false><<<g, blk, 0, stream>>>(B0, A0, pred, acc, B0, A0, pred, acc, infb);
        skel_iter_kernel<false><<<g, blk, 0, stream>>>(A0, B0, pred, acc, A0, B0, pred, acc, infb);
        skel_iter_kernel<true ><<<g, blk, 0, stream>>>(B0, nullptr, pred, acc, B0, nullptr, pred, acc, infb);
        skel_iter_kernel<false><<<g, blk, 0, stream>>>(pred, A0, tgt, acc + 2, pred, A0, tgt, acc + 2, infb);
        skel_iter_kernel<false><<<g, blk, 0, stream>>>(A0, B0, tgt, acc + 2, A0, B0, tgt, acc + 2, infb);
        skel_iter_kernel<false><<<g, blk, 0, stream>>>(B0, A0, tgt, acc + 2, B0, A0, tgt, acc + 2, infb);
        skel_iter_kernel<false><<<g, blk, 0, stream>>>(A0, B0, tgt, acc + 2, A0, B0, tgt, acc + 2, infb);
        skel_iter_kernel<true ><<<g, blk, 0, stream>>>(B0, nullptr, tgt, acc + 2, B0, nullptr, tgt, acc + 2, infb);
    }

    final_kernel<<<1, 1, 0, stream>>>(acc, out);
}